// Round 5
// baseline (147.916 us; speedup 1.0000x reference)
//
#include <hip/hip_runtime.h>
#include <cstdint>

#define PI_F 3.14159265358979323846f

__device__ __forceinline__ float fract_(float x)  { return __builtin_amdgcn_fractf(x); }
__device__ __forceinline__ float sin2pi_(float r) { return __builtin_amdgcn_sinf(r); }  // sin(2*pi*r)
__device__ __forceinline__ float cos2pi_(float r) { return __builtin_amdgcn_cosf(r); }  // cos(2*pi*r)

// ---------------------------------------------------------------------------
// Kernel A: compress z_real/z_imag (+-1) to sign bitmasks, one 32-bit word
// per thread (bit j of word t = sign(z[32t+j]) < 0). 8 float4 loads per array
// per thread; each 128B line consumed entirely by one thread -> ideal 67 MB
// read + 2 MB write, fully latency-tolerant (1024 blocks).
// ---------------------------------------------------------------------------
extern "C" __global__ void __launch_bounds__(256)
pack_signs(const float4* __restrict__ zr, const float4* __restrict__ zi,
           uint32_t* __restrict__ pr, uint32_t* __restrict__ pim) {
    const int t = blockIdx.x * 256 + threadIdx.x;     // word index
    uint32_t wr = 0u, wi = 0u;
    #pragma unroll
    for (int q = 0; q < 8; ++q) {
        const float4 a = zr[t * 8 + q];
        const float4 b = zi[t * 8 + q];
        wr |= ((uint32_t)(a.x < 0.f) << (4 * q))     | ((uint32_t)(a.y < 0.f) << (4 * q + 1))
            | ((uint32_t)(a.z < 0.f) << (4 * q + 2)) | ((uint32_t)(a.w < 0.f) << (4 * q + 3));
        wi |= ((uint32_t)(b.x < 0.f) << (4 * q))     | ((uint32_t)(b.y < 0.f) << (4 * q + 1))
            | ((uint32_t)(b.z < 0.f) << (4 * q + 2)) | ((uint32_t)(b.w < 0.f) << (4 * q + 3));
    }
    pr[t] = wr;
    pim[t] = wi;
}

// ---------------------------------------------------------------------------
// Kernel B: refiner, bit-identical trajectory to the round-1 kernel
// (absmax 36.0). 8 waves/block (512 thr) -> 4096 waves = 4 waves/SIMD.
// Wave wv = 2*w_+h owns chains m = {2h, 2h+1} of round-1 wave group w_;
// fold order ((r0+r1)+(r2+r3)) + ((r4+r5)+(r6+r7)) reproduces round-1's
// per-wave (a0+a1)+(a2+a3) then (S0+S1)+(S2+S3) exactly (proven round 3).
// Head (tanhf/sinf/cosf/update) is computed redundantly by EVERY wave from
// its own u0,u1 copy -- identical bits, no wave-0 critical path (round-3
// lesson). Softplus params hoisted (round-4), 1 barrier/iter via parity
// double-buffered reduction.
// ---------------------------------------------------------------------------
extern "C" __global__ void __launch_bounds__(512, 4)
refine(const float* __restrict__ th0, const float* __restrict__ r0,
       const float* __restrict__ a_th_raw, const float* __restrict__ a_r_raw,
       const float* __restrict__ l_th_raw, const float* __restrict__ l_r_raw,
       const uint32_t* __restrict__ pr, const uint32_t* __restrict__ pim,
       float* __restrict__ out) {
    const int tid  = threadIdx.x;
    const int lane = tid & 63;
    const int wv   = tid >> 6;               // wave 0..7
    const int w_   = wv >> 1;                // round-1 wave group 0..3
    const int mA   = 2 * (wv & 1);           // this wave's chains: mA, mA+1
    const int item = blockIdx.x * 64 + lane;

    __shared__ float sp[4][10];              // ath, ar, lth, lr per step
    __shared__ float red[2][8][64];          // parity-double-buffered reduce

    if (tid < 40) {
        const int a = tid / 10, i = tid % 10;
        const float* src = (a == 0) ? a_th_raw : (a == 1) ? a_r_raw
                         : (a == 2) ? l_th_raw : l_r_raw;
        const float v  = log1pf(expf(src[i]));           // verbatim round-1 expr
        const float hi = (a < 2) ? 0.2f : 1.0f;
        sp[a][i] = fminf(fmaxf(v, 1e-6f), hi);
    }

    // sign bits for group w_'s 64 k's (2 words per component)
    const uint32_t br0 = pr [item * 8 + w_ * 2 + 0];
    const uint32_t br1 = pr [item * 8 + w_ * 2 + 1];
    const uint32_t bi0 = pim[item * 8 + w_ * 2 + 0];
    const uint32_t bi1 = pim[item * 8 + w_ * 2 + 1];

    // u0 = atanh(theta/60), u1 = atanh(2*(r/2000)-1) -- verbatim round-1,
    // computed by every thread (redundant, bit-identical across waves)
    float y = th0[item] * (1.0f / 60.0f);
    y = fminf(fmaxf(y, -1.0f + 1e-6f), 1.0f - 1e-6f);
    float u0 = atanhf(y);
    float sR = r0[item] * (1.0f / 2000.0f);
    sR = fminf(fmaxf(sR, 1e-6f), 1.0f - 1e-6f);
    float u1 = atanhf(2.0f * sR - 1.0f);

    const float w64 = (float)(w_ * 64);

    __syncthreads();                          // sp[] ready

    for (int t = 0; t < 10; ++t) {
        const float ath = sp[0][t], ar = sp[1][t], lth = sp[2][t], lr = sp[3][t];

        // ---- head, verbatim round-1, redundant in every wave ----
        const float T0 = tanhf(u0), T1 = tanhf(u1);
        const float th_rad = (PI_F / 3.0f) * T0;          // 60*T0 deg -> rad
        const float sth = sinf(th_rad), cth = cosf(th_rad);
        const float r   = 1000.0f * (T1 + 1.0f);
        const float crev = 0.5f * sth - 2e-4f * r;        // revolutions per unit k

        const float d4 = fract_(4.0f * crev);
        const float C4 = cos2pi_(d4), S4 = sin2pi_(d4);   // rotation e^{i*2pi*4*crev}

        // ---- two chains, verbatim round-1 inner arithmetic ----
        float c[2], s[2], kf[2], acc[2];
        #pragma unroll
        for (int mm = 0; mm < 2; ++mm) {
            const float k0 = w64 + (float)(mA + mm);
            const float rv = fract_(k0 * crev);
            c[mm]   = cos2pi_(rv);
            s[mm]   = sin2pi_(rv);
            kf[mm]  = k0;
            acc[mm] = 0.0f;
        }

        #pragma unroll
        for (int j = 0; j < 16; ++j) {
            #pragma unroll
            for (int mm = 0; mm < 2; ++mm) {
                const int kl = (mA + mm) + 4 * j;          // 0..63, compile-time
                const uint32_t wr = (kl < 32) ? br0 : br1;
                const uint32_t wi = (kl < 32) ? bi0 : bi1;
                const int sh = 31 - (kl & 31);
                const uint32_t mre = (wr << sh) & 0x80000000u;
                const uint32_t mim = (wi << sh) & 0x80000000u;
                const float cs = c[mm], ss = s[mm];
                const float zc = __uint_as_float(__float_as_uint(cs) ^ mim); // z_im*cos
                const float zs = __uint_as_float(__float_as_uint(ss) ^ mre); // z_re*sin
                const float w0 = zc - zs;
                // cubic sigma term: -sin(4phi)/786432 = -s*c*(1-2s^2)/196608
                const float u2 = ss * ss;
                const float t2 = fmaf(-2.0f, u2, 1.0f);
                const float sc = ss * cs;
                const float v  = sc * t2;
                const float Wk = fmaf(v, -(1.0f / 196608.0f), w0 * 0.0625f);
                acc[mm] = fmaf(kf[mm], Wk, acc[mm]);
                kf[mm] += 4.0f;
                const float tA = ss * S4;
                const float tB = cs * S4;
                c[mm] = fmaf(cs, C4, -tA);
                s[mm] = fmaf(ss, C4, tB);
            }
        }

        // partial = round-1's (acc[2h] + acc[2h+1]) of group w_
        const int p = t & 1;                   // parity buffer; WAR protected
        red[p][wv][lane] = acc[0] + acc[1];    // by next iteration's barrier
        __syncthreads();

        // round-1 exact fold tree, computed redundantly by every thread
        const float S0 = red[p][0][lane] + red[p][1][lane];   // group 0
        const float S1 = red[p][2][lane] + red[p][3][lane];   // group 1
        const float S2 = red[p][4][lane] + red[p][5][lane];   // group 2
        const float S3 = red[p][6][lane] + red[p][7][lane];   // group 3
        const float S  = (S0 + S1) + (S2 + S3);

        // ---- update, verbatim round-1, redundant in every wave ----
        const float g0 = -(PI_F * PI_F / 3.0f) * cth * (1.0f - T0 * T0) * S;
        const float g1 = 0.4f * PI_F * (1.0f - T1 * T1) * S;
        const float den0 = fmaxf(fabsf(g0), 1e-6f) + lth;
        const float den1 = fmaxf(fabsf(g1), 1e-6f) + lr;
        float st0 = ath * g0 / den0;
        float st1 = ar  * g1 / den1;
        st0 = fminf(fmaxf(st0, -0.1f), 0.1f);
        st1 = fminf(fmaxf(st1, -0.1f), 0.1f);
        u0 -= st0;
        u1 -= st1;
    }

    if (wv == 0) {
        const float thT = 60.0f * tanhf(u0);
        const float rT  = 1000.0f * (tanhf(u1) + 1.0f);
        reinterpret_cast<float2*>(out)[item] = make_float2(thT, rT);
    }
}

extern "C" void kernel_launch(void* const* d_in, const int* in_sizes, int n_in,
                              void* d_out, int out_size, void* d_ws, size_t ws_size,
                              hipStream_t stream) {
    const float* zr   = (const float*)d_in[0];
    const float* zi   = (const float*)d_in[1];
    const float* th0  = (const float*)d_in[2];
    const float* r0   = (const float*)d_in[3];
    const float* athr = (const float*)d_in[4];
    const float* arr  = (const float*)d_in[5];
    const float* lthr = (const float*)d_in[6];
    const float* lrr  = (const float*)d_in[7];

    const int B  = in_sizes[2];          // 32768
    const int BK = in_sizes[0];          // B*K = 8388608

    uint32_t* pr  = (uint32_t*)d_ws;     // B*8 words = 1 MB
    uint32_t* pim = pr + (size_t)B * 8;  // B*8 words = 1 MB

    pack_signs<<<(BK / 32) / 256, 256, 0, stream>>>((const float4*)zr, (const float4*)zi,
                                                    pr, pim);
    refine<<<B / 64, 512, 0, stream>>>(th0, r0, athr, arr, lthr, lrr, pr, pim,
                                       (float*)d_out);
}

// Round 6
// 138.807 us; speedup vs baseline: 1.0656x; 1.0656x over previous
//
#include <hip/hip_runtime.h>
#include <cstdint>

#define PI_F 3.14159265358979323846f

typedef float v2f __attribute__((ext_vector_type(2)));

__device__ __forceinline__ float fract_(float x)  { return __builtin_amdgcn_fractf(x); }
__device__ __forceinline__ float sin2pi_(float r) { return __builtin_amdgcn_sinf(r); }  // sin(2*pi*r)
__device__ __forceinline__ float cos2pi_(float r) { return __builtin_amdgcn_cosf(r); }  // cos(2*pi*r)
__device__ __forceinline__ v2f  splat2(float x)   { v2f r; r.x = x; r.y = x; return r; }

// ---------------------------------------------------------------------------
// Kernel A: compress z_real/z_imag (+-1) to sign bitmasks, one 32-bit word
// per thread (bit j of word t = sign(z[32t+j]) < 0). 8 float4 loads per array
// per thread; each 128B line consumed entirely by one thread -> ideal 67 MB
// read + 2 MB write, fully latency-tolerant (1024 blocks). Verbatim round-4.
// ---------------------------------------------------------------------------
extern "C" __global__ void __launch_bounds__(256)
pack_signs(const float4* __restrict__ zr, const float4* __restrict__ zi,
           uint32_t* __restrict__ pr, uint32_t* __restrict__ pim) {
    const int t = blockIdx.x * 256 + threadIdx.x;     // word index
    uint32_t wr = 0u, wi = 0u;
    #pragma unroll
    for (int q = 0; q < 8; ++q) {
        const float4 a = zr[t * 8 + q];
        const float4 b = zi[t * 8 + q];
        wr |= ((uint32_t)(a.x < 0.f) << (4 * q))     | ((uint32_t)(a.y < 0.f) << (4 * q + 1))
            | ((uint32_t)(a.z < 0.f) << (4 * q + 2)) | ((uint32_t)(a.w < 0.f) << (4 * q + 3));
        wi |= ((uint32_t)(b.x < 0.f) << (4 * q))     | ((uint32_t)(b.y < 0.f) << (4 * q + 1))
            | ((uint32_t)(b.z < 0.f) << (4 * q + 2)) | ((uint32_t)(b.w < 0.f) << (4 * q + 3));
    }
    pr[t] = wr;
    pim[t] = wi;
}

// ---------------------------------------------------------------------------
// Kernel B: round-4 refiner (best so far, absmax 36.0) with ONE bit-neutral
// change: the 4 chains are processed as 2 chain-PAIRS in <2 x float> vectors
// so the fp32 mul/fma/add of the inner step lower to packed VOP3P
// (v_pk_fma_f32 etc., dual fp32/instr, IEEE-identical per component).
// All FP expressions, seeds, fold order, head, update: verbatim round-1
// -> trajectory bit-identical.
// Structure: 4 waves/block (256 thr), wave w owns k in [64w, 64w+64);
// softplus hoisted; parity double-buffered 1-barrier reduction.
// ---------------------------------------------------------------------------
extern "C" __global__ void __launch_bounds__(256)
refine(const float* __restrict__ th0, const float* __restrict__ r0,
       const float* __restrict__ a_th_raw, const float* __restrict__ a_r_raw,
       const float* __restrict__ l_th_raw, const float* __restrict__ l_r_raw,
       const uint32_t* __restrict__ pr, const uint32_t* __restrict__ pim,
       float* __restrict__ out) {
    const int lane = threadIdx.x & 63;
    const int w    = threadIdx.x >> 6;       // wave id 0..3, owns k in [w*64, w*64+64)
    const int item = blockIdx.x * 64 + lane;

    __shared__ float sp[4][10];              // ath, ar, lth, lr per step
    __shared__ float red[2][4][64];          // parity-double-buffered reduce

    if (threadIdx.x < 40) {
        const int a = threadIdx.x / 10, i = threadIdx.x % 10;
        const float* src = (a == 0) ? a_th_raw : (a == 1) ? a_r_raw
                         : (a == 2) ? l_th_raw : l_r_raw;
        const float v  = log1pf(expf(src[i]));           // verbatim round-1 expr
        const float hi = (a < 2) ? 0.2f : 1.0f;
        sp[a][i] = fminf(fmaxf(v, 1e-6f), hi);
    }

    // sign bits for this wave's 64 k's (2 words per component)
    const uint32_t br0 = pr [item * 8 + w * 2 + 0];
    const uint32_t br1 = pr [item * 8 + w * 2 + 1];
    const uint32_t bi0 = pim[item * 8 + w * 2 + 0];
    const uint32_t bi1 = pim[item * 8 + w * 2 + 1];

    // u0 = atanh(theta/60), u1 = atanh(2*(r/2000)-1), with reference clips
    float y = th0[item] * (1.0f / 60.0f);
    y = fminf(fmaxf(y, -1.0f + 1e-6f), 1.0f - 1e-6f);
    float u0 = atanhf(y);
    float sR = r0[item] * (1.0f / 2000.0f);
    sR = fminf(fmaxf(sR, 1e-6f), 1.0f - 1e-6f);
    float u1 = atanhf(2.0f * sR - 1.0f);

    const float w64 = (float)(w * 64);

    __syncthreads();                          // sp[] ready

    for (int t = 0; t < 10; ++t) {
        const float ath = sp[0][t], ar = sp[1][t], lth = sp[2][t], lr = sp[3][t];

        const float T0 = tanhf(u0), T1 = tanhf(u1);
        const float th_rad = (PI_F / 3.0f) * T0;          // 60*T0 deg -> rad
        const float sth = sinf(th_rad), cth = cosf(th_rad);
        const float r   = 1000.0f * (T1 + 1.0f);
        const float crev = 0.5f * sth - 2e-4f * r;        // revolutions per unit k

        // rotation step e^{i*2pi*4*crev}
        const float d4 = fract_(4.0f * crev);
        const v2f C4 = splat2(cos2pi_(d4));
        const v2f S4 = splat2(sin2pi_(d4));

        // chain pairs: pair p holds chains (2p, 2p+1)
        v2f c[2], s[2], kf[2], acc[2];
        #pragma unroll
        for (int p2 = 0; p2 < 2; ++p2) {
            const float k0a = w64 + (float)(2 * p2);
            const float k0b = w64 + (float)(2 * p2 + 1);
            const float rva = fract_(k0a * crev);
            const float rvb = fract_(k0b * crev);
            v2f cc, ssv, kk;
            cc.x  = cos2pi_(rva);  cc.y  = cos2pi_(rvb);
            ssv.x = sin2pi_(rva);  ssv.y = sin2pi_(rvb);
            kk.x  = k0a;           kk.y  = k0b;
            c[p2]   = cc;
            s[p2]   = ssv;
            kf[p2]  = kk;
            acc[p2] = splat2(0.0f);
        }

        const v2f mtwo = splat2(-2.0f);
        const v2f one  = splat2(1.0f);
        const v2f cub  = splat2(-(1.0f / 196608.0f));
        const v2f four = splat2(4.0f);

        #pragma unroll
        for (int j = 0; j < 16; ++j) {
            #pragma unroll
            for (int p2 = 0; p2 < 2; ++p2) {
                const int klA = 2 * p2 + 4 * j;            // chains 2p2, 2p2+1
                const int klB = klA + 1;                   // compile-time
                const uint32_t wr = (klA < 32) ? br0 : br1;
                const uint32_t wi = (klA < 32) ? bi0 : bi1;
                const uint32_t mreA = (wr << (31 - (klA & 31))) & 0x80000000u;
                const uint32_t mreB = (wr << (31 - (klB & 31))) & 0x80000000u;
                const uint32_t mimA = (wi << (31 - (klA & 31))) & 0x80000000u;
                const uint32_t mimB = (wi << (31 - (klB & 31))) & 0x80000000u;
                const v2f cs = c[p2], ss = s[p2];
                v2f zc, zs;                                 // z_im*cos, z_re*sin
                zc.x = __uint_as_float(__float_as_uint(cs.x) ^ mimA);
                zc.y = __uint_as_float(__float_as_uint(cs.y) ^ mimB);
                zs.x = __uint_as_float(__float_as_uint(ss.x) ^ mreA);
                zs.y = __uint_as_float(__float_as_uint(ss.y) ^ mreB);
                const v2f w0 = zc - zs;
                // cubic sigma term: -sin(4phi)/786432 = -s*c*(1-2s^2)/196608
                const v2f u2 = ss * ss;
                const v2f t2 = __builtin_elementwise_fma(mtwo, u2, one);
                const v2f sc = ss * cs;
                const v2f v  = sc * t2;
                const v2f W  = __builtin_elementwise_fma(v, cub, w0 * 0.0625f);
                acc[p2] = __builtin_elementwise_fma(kf[p2], W, acc[p2]);
                kf[p2]  = kf[p2] + four;
                // rotate phase by 4*crev revolutions
                const v2f tA = ss * S4;
                const v2f tB = cs * S4;
                c[p2] = __builtin_elementwise_fma(cs, C4, -tA);
                s[p2] = __builtin_elementwise_fma(ss, C4, tB);
            }
        }
        // round-1 fold: (acc0 + acc1) + (acc2 + acc3)
        float S = (acc[0].x + acc[0].y) + (acc[1].x + acc[1].y);

        // cross-wave reduce, parity double-buffered (WAR on buffer p=t&1 is
        // protected by the barrier of iteration t+1)
        const int p = t & 1;
        red[p][w][lane] = S;
        __syncthreads();
        S = (red[p][0][lane] + red[p][1][lane]) + (red[p][2][lane] + red[p][3][lane]);

        // gradient of -loglike wrt u, then normalized clipped step (verbatim)
        const float g0 = -(PI_F * PI_F / 3.0f) * cth * (1.0f - T0 * T0) * S;
        const float g1 = 0.4f * PI_F * (1.0f - T1 * T1) * S;
        const float den0 = fmaxf(fabsf(g0), 1e-6f) + lth;
        const float den1 = fmaxf(fabsf(g1), 1e-6f) + lr;
        float st0 = ath * g0 / den0;
        float st1 = ar  * g1 / den1;
        st0 = fminf(fmaxf(st0, -0.1f), 0.1f);
        st1 = fminf(fmaxf(st1, -0.1f), 0.1f);
        u0 -= st0;
        u1 -= st1;
    }

    if (w == 0) {
        const float thT = 60.0f * tanhf(u0);
        const float rT  = 1000.0f * (tanhf(u1) + 1.0f);
        reinterpret_cast<float2*>(out)[item] = make_float2(thT, rT);
    }
}

extern "C" void kernel_launch(void* const* d_in, const int* in_sizes, int n_in,
                              void* d_out, int out_size, void* d_ws, size_t ws_size,
                              hipStream_t stream) {
    const float* zr   = (const float*)d_in[0];
    const float* zi   = (const float*)d_in[1];
    const float* th0  = (const float*)d_in[2];
    const float* r0   = (const float*)d_in[3];
    const float* athr = (const float*)d_in[4];
    const float* arr  = (const float*)d_in[5];
    const float* lthr = (const float*)d_in[6];
    const float* lrr  = (const float*)d_in[7];

    const int B  = in_sizes[2];          // 32768
    const int BK = in_sizes[0];          // B*K = 8388608

    uint32_t* pr  = (uint32_t*)d_ws;     // B*8 words = 1 MB
    uint32_t* pim = pr + (size_t)B * 8;  // B*8 words = 1 MB

    pack_signs<<<(BK / 32) / 256, 256, 0, stream>>>((const float4*)zr, (const float4*)zi,
                                                    pr, pim);
    refine<<<B / 64, 256, 0, stream>>>(th0, r0, athr, arr, lthr, lrr, pr, pim,
                                       (float*)d_out);
}